// Round 15
// baseline (240.534 us; speedup 1.0000x reference)
//
#include <hip/hip_runtime.h>
#include <hip/hip_bf16.h>

#define N_NODES 50000
#define K_NB 16
#define E_EDGES 800000
#define B_MOL 1024
#define MAXM_M 48
#define FDIM 9
#define ADIM 10
#define H 64
#define NEG_INF_F (-1e9f)
#define PRE_NODE_BLOCKS 196  /* 1 thread per node */
#define EDGE_BLOCKS 3125     /* 256 edges per block */

typedef __bf16 bf16x8 __attribute__((ext_vector_type(8)));
typedef float f32x4 __attribute__((ext_vector_type(4)));
union UB { uint4 u; bf16x8 v; };

__device__ inline float readlane_f(float v, int l) {
    return __int_as_float(__builtin_amdgcn_readlane(__float_as_int(v), l));
}
__device__ inline int readlane_i(int v, int l) {
    return __builtin_amdgcn_readlane(v, l);
}
__device__ inline float bf2f(unsigned u) {         // u = zero-extended bf16
    return __uint_as_float(u << 16);
}
__device__ inline unsigned short f2bf(float f) {   // round-to-nearest-even
    unsigned x = __float_as_uint(f);
    return (unsigned short)((x + 0x7fffu + ((x >> 16) & 1u)) >> 16);
}

// Raw gather, wave-uniform SGPR base + per-lane VGPR byte offset.
#define GLOAD_U16(dst, voff, sbase) \
    asm volatile("global_load_ushort %0, %1, %2" : "=v"(dst) : "v"(voff), "s"(sbase))
#define GLOAD_F32(dst, voff, sbase) \
    asm volatile("global_load_dword %0, %1, %2" : "=v"(dst) : "v"(voff), "s"(sbase))

#define DRAIN16(a) \
    asm volatile("s_waitcnt vmcnt(0)" \
        : "+v"(a[0]), "+v"(a[1]), "+v"(a[2]), "+v"(a[3]), \
          "+v"(a[4]), "+v"(a[5]), "+v"(a[6]), "+v"(a[7]), \
          "+v"(a[8]), "+v"(a[9]), "+v"(a[10]), "+v"(a[11]), \
          "+v"(a[12]), "+v"(a[13]), "+v"(a[14]), "+v"(a[15]))
#define HOLD16(a) \
    asm volatile("" \
        : "+v"(a[0]), "+v"(a[1]), "+v"(a[2]), "+v"(a[3]), \
          "+v"(a[4]), "+v"(a[5]), "+v"(a[6]), "+v"(a[7]), \
          "+v"(a[8]), "+v"(a[9]), "+v"(a[10]), "+v"(a[11]), \
          "+v"(a[12]), "+v"(a[13]), "+v"(a[14]), "+v"(a[15]))

// ---------------------------------------------------------------------------
// Fold all weight algebra (single block):
//   wa/ca (iter-1 edge logit), wv9/cv (iter-1 node logit),
//   WintT[64][128]: interleaved W_gat/Wm_gat transpose (k_gat2 MFMA B),
//   WcatT[64][32]:  rows k: 0..8=W3, 9..18=W2, 19=c3, 20=c2, rest 0
//                   (k_gat1 epilogue MFMA B),
//   vabT[16][64]:   row0=va=W_gat@a1, row1=vb=Wm_gat@a2 (t1B/t2B MFMA B).
// ---------------------------------------------------------------------------
__global__ __launch_bounds__(256) void k_fold(
    const float* __restrict__ W_emb, const float* __restrict__ b_emb,
    const float* __restrict__ W_dist, const float* __restrict__ b_dist,
    const float* __restrict__ W_gat, const float* __restrict__ Wm_gat,
    const float* __restrict__ a_gat,
    float* __restrict__ wa, float* __restrict__ ca,
    float* __restrict__ wv9, float* __restrict__ cv,
    unsigned short* __restrict__ WintT, unsigned short* __restrict__ WcatT,
    unsigned short* __restrict__ vabT)
{
    __shared__ float s_va[64], s_vb[64];
    int tid = threadIdx.x;
    int h = tid & 63, g = tid >> 6;
    if (g == 0) {            // va[h] = W_gat[h,:] . a1
        float acc = 0.f;
        for (int t = 0; t < H; ++t) acc += W_gat[h * H + t] * a_gat[t];
        s_va[h] = acc;
    } else if (g == 1) {     // vb[h] = Wm_gat[h,:] . a2
        float acc = 0.f;
        for (int t = 0; t < H; ++t) acc += Wm_gat[h * H + t] * a_gat[H + t];
        s_vb[h] = acc;
    }
    __syncthreads();
    for (int q = tid; q < H * 2 * H; q += 256) {  // WintT[n][k]
        int n = q >> 7, k = q & 127;
        float v = (k & 1) ? Wm_gat[(k >> 1) * H + n] : W_gat[(k >> 1) * H + n];
        WintT[q] = f2bf(v);
    }
    for (int q = tid; q < 64 * 32; q += 256) {    // WcatT[n][k]
        int n = q >> 5, k = q & 31;
        float acc = 0.f;
        if (k < 9) {
            for (int t = 0; t < H; ++t) acc += W_emb[k * H + t] * W_gat[t * H + n];
        } else if (k < 19) {
            for (int t = 0; t < H; ++t) acc += W_dist[(k - 9) * H + t] * Wm_gat[t * H + n];
        } else if (k == 19) {
            for (int t = 0; t < H; ++t) acc += b_emb[t] * W_gat[t * H + n];
        } else if (k == 20) {
            for (int t = 0; t < H; ++t) acc += b_dist[t] * Wm_gat[t * H + n];
        }
        WcatT[q] = f2bf(acc);
    }
    for (int q = tid; q < 16 * 64; q += 256) {    // vabT[n][k]
        int n = q >> 6, k = q & 63;
        float v = (n == 0) ? s_va[k] : (n == 1) ? s_vb[k] : 0.f;
        vabT[q] = f2bf(v);
    }
    if (tid < ADIM) {                         // wa
        float acc = 0.f;
        for (int t = 0; t < H; ++t) acc += W_dist[tid * H + t] * s_vb[t];
        wa[tid] = acc;
    } else if (tid == ADIM) {                 // ca
        float acc = 0.f;
        for (int t = 0; t < H; ++t) acc += b_dist[t] * s_vb[t];
        ca[0] = acc;
    } else if (tid >= 16 && tid < 16 + FDIM) {// wv9
        int j = tid - 16;
        float acc = 0.f;
        for (int t = 0; t < H; ++t) acc += W_emb[j * H + t] * s_va[t];
        wv9[j] = acc;
    } else if (tid == 31) {                   // cv
        float acc = 0.f;
        for (int t = 0; t < H; ++t) acc += b_emb[t] * s_va[t];
        cv[0] = acc;
    }
}

// ---------------------------------------------------------------------------
// Pre-pass: t1A + tfp records (node side); emsg records + sue (edge side).
// ---------------------------------------------------------------------------
__global__ __launch_bounds__(256) void k_pre(
    const float* __restrict__ tf, const float* __restrict__ fdg,
    const float* __restrict__ rij,
    const int* __restrict__ su, const int* __restrict__ sul,
    const float* __restrict__ wa, const float* __restrict__ ca,
    const float* __restrict__ wv9, const float* __restrict__ cv,
    float* __restrict__ t1A, unsigned short* __restrict__ tfp,
    unsigned short* __restrict__ emsg, int* __restrict__ sue)
{
    int bid = blockIdx.x;
    if (bid < PRE_NODE_BLOCKS) {
        int n = bid * 256 + threadIdx.x;
        if (n == 0) {                        // zero pad row
            t1A[0] = 0.f;
            uint4 z = make_uint4(0, 0, 0, 0);
            ((uint4*)tfp)[0] = z; ((uint4*)tfp)[1] = z;
        }
        if (n >= N_NODES) return;
        float f[FDIM];
        float acc = cv[0];
#pragma unroll
        for (int j = 0; j < FDIM; ++j) {
            f[j] = tf[n * FDIM + j];
            acc += f[j] * wv9[j];
        }
        t1A[n + 1] = acc;
        unsigned rec[8];
#pragma unroll
        for (int j = 0; j < 4; ++j)
            rec[j] = (unsigned)f2bf(f[2 * j]) | ((unsigned)f2bf(f[2 * j + 1]) << 16);
        rec[4] = (unsigned)f2bf(f[8]);
        rec[5] = 0; rec[6] = 0; rec[7] = 0;
        uint4* dst = (uint4*)(tfp + (size_t)(n + 1) * 16);
        dst[0] = make_uint4(rec[0], rec[1], rec[2], rec[3]);
        dst[1] = make_uint4(rec[4], rec[5], rec[6], rec[7]);
    } else {
        int e = (bid - PRE_NODE_BLOCKS) * 256 + threadIdx.x;
        float f[ADIM];
#pragma unroll
        for (int j = 0; j < FDIM; ++j) f[j] = fdg[(size_t)e * FDIM + j];
        f[FDIM] = rij[e];
        float acc = ca[0];
#pragma unroll
        for (int j = 0; j < ADIM; ++j) acc += f[j] * wa[j];
        unsigned rec[8];
#pragma unroll
        for (int j = 0; j < 5; ++j)
            rec[j] = (unsigned)f2bf(f[2 * j]) | ((unsigned)f2bf(f[2 * j + 1]) << 16);
        rec[5] = __float_as_uint(acc);
        rec[6] = 0; rec[7] = 0;
        uint4* dst = (uint4*)(emsg + (size_t)e * 16);
        dst[0] = make_uint4(rec[0], rec[1], rec[2], rec[3]);
        dst[1] = make_uint4(rec[4], rec[5], rec[6], rec[7]);
        sue[e] = (sul[e] > 0) ? su[e] : 0;
    }
}

// ---------------------------------------------------------------------------
// GAT iter 1 — FUSED gather + MFMA epilogue (round-15, mirrors the proven
// round-14 k_gat2 fusion). 1024-thread blocks = 16 waves = 16 hp2 rows.
// Phase 1 (per wave): logit + 32 gathers + softmax -> A-row
//   [fr(9) | frm(10) | beta | 1 | 0...] staged in LDS (stride 40: 2-way max).
// Phase 2 (waves 0-3): one mfma_f32_16x16x32_bf16 per 16-col strip vs
//   WcatT -> o = elu(...) -> hp2bf + LDS stage (stride 72: 2-way max).
// Phase 3 (wave 0): t1B/t2B = bf16(o) @ [va|vb] via two MFMAs vs vabT.
// Row 0 (pad) gets an all-zero A row (the "1" flag is 0) -> hp2=0, t=0.
// ---------------------------------------------------------------------------
__global__ __launch_bounds__(1024) void k_gat1(
    const int* __restrict__ sse, const int* __restrict__ bsc,
    const float* __restrict__ t1A, const unsigned short* __restrict__ tfp,
    const unsigned short* __restrict__ emsg,
    const unsigned short* __restrict__ WcatT,
    const unsigned short* __restrict__ vabT,
    unsigned short* __restrict__ hp2bf, float* __restrict__ t1B,
    float* __restrict__ t2B)
{
    __shared__ __align__(16) unsigned short s_a[16][40];
    __shared__ __align__(16) unsigned short s_o[16][72];
    int wave = threadIdx.x >> 6;
    int lane = threadIdx.x & 63;
    int row0 = blockIdx.x * 16;
    int row  = row0 + wave;
    int n    = row - 1;                    // node (row 0 = pad)

    float fr = 0.f, frm = 0.f, beta = 0.f;
    if (n >= 0 && n < N_NODES) {
        int kidx = 0, ke = 0;
        float lg = NEG_INF_F;
        if (lane < K_NB) {
            kidx = sse[n * K_NB + lane];
            ke   = bsc[n * K_NB + lane];
            float g2 = __uint_as_float(*(const unsigned*)(emsg + (size_t)ke * 16 + 10));
            float p = t1A[kidx] + g2;
            p = (p > 0.f) ? p : 0.2f * p;
            lg = (kidx == 0) ? NEG_INF_F : p;
        }
        unsigned wn_u[K_NB], wm_u[K_NB];
        int offr = (lane & 15) * 2;
#pragma unroll
        for (int k = 0; k < K_NB; ++k) {
            const unsigned short* pk = tfp + (size_t)readlane_i(kidx, k) * 16;
            GLOAD_U16(wn_u[k], offr, pk);
        }
#pragma unroll
        for (int k = 0; k < K_NB; ++k) {
            const unsigned short* pe = emsg + (size_t)readlane_i(ke, k) * 16;
            GLOAD_U16(wm_u[k], offr, pe);
        }
        float m = lg;
#pragma unroll
        for (int o = 8; o > 0; o >>= 1) m = fmaxf(m, __shfl_xor(m, o, 64));
        float ex = __expf(lg - m);
        float s = ex;
#pragma unroll
        for (int o = 8; o > 0; o >>= 1) s += __shfl_xor(s, o, 64);
        float alpha = ex / s;

        DRAIN16(wn_u);
        HOLD16(wm_u);
#pragma unroll
        for (int k = 0; k < K_NB; ++k) {
            float ak = readlane_f(alpha, k);
            fr  += ak * bf2f(wn_u[k]);
            frm += ak * bf2f(wm_u[k]);
            beta += (readlane_i(kidx, k) > 0) ? ak : 0.f;
        }
    }
    if (lane < FDIM)  s_a[wave][lane] = f2bf(fr);
    if (lane < ADIM)  s_a[wave][FDIM + lane] = f2bf(frm);
    if (lane == 10)   s_a[wave][19] = f2bf(beta);
    if (lane == 11)   s_a[wave][20] = (row == 0) ? 0 : (unsigned short)0x3F80;
    if (lane >= 21 && lane < 32) s_a[wave][lane] = 0;
    __syncthreads();

    int m16 = lane & 15, q = lane >> 4;
    if (wave < 4) {                        // strip t = wave: cols t*16..+15
        int t = wave;
        UB ub; ub.u = *(const uint4*)(WcatT + (size_t)(t * 16 + m16) * 32 + q * 8);
        UB ua; ua.u = *(const uint4*)&s_a[m16][q * 8];
        f32x4 acc = (f32x4){0.f, 0.f, 0.f, 0.f};
        acc = __builtin_amdgcn_mfma_f32_16x16x32_bf16(ua.v, ub.v, acc, 0, 0, 0);
#pragma unroll
        for (int r = 0; r < 4; ++r) {
            int rr = row0 + q * 4 + r;
            float v = acc[r];
            float o = (v > 0.f) ? v : expm1f(v);
            unsigned short ob = f2bf(o);
            s_o[q * 4 + r][t * 16 + m16] = ob;
            if (rr <= N_NODES) hp2bf[(size_t)rr * H + t * 16 + m16] = ob;
        }
    }
    __syncthreads();
    if (wave == 0) {                       // t1B/t2B = bf16(o) @ [va|vb]
        UB a0, a1, b0, b1;
        a0.u = *(const uint4*)&s_o[m16][q * 8];
        a1.u = *(const uint4*)&s_o[m16][32 + q * 8];
        b0.u = *(const uint4*)(vabT + (size_t)m16 * 64 + q * 8);
        b1.u = *(const uint4*)(vabT + (size_t)m16 * 64 + 32 + q * 8);
        f32x4 acc = (f32x4){0.f, 0.f, 0.f, 0.f};
        acc = __builtin_amdgcn_mfma_f32_16x16x32_bf16(a0.v, b0.v, acc, 0, 0, 0);
        acc = __builtin_amdgcn_mfma_f32_16x16x32_bf16(a1.v, b1.v, acc, 0, 0, 0);
        if (m16 < 2) {
#pragma unroll
            for (int r = 0; r < 4; ++r) {
                int rr = row0 + q * 4 + r;
                if (rr <= N_NODES) {
                    if (m16 == 0) t1B[rr] = acc[r];
                    else          t2B[rr] = acc[r];
                }
            }
        }
    }
}

// ---------------------------------------------------------------------------
// GAT iter 2 — FUSED gather + MFMA projection (round-14, unchanged).
// ---------------------------------------------------------------------------
__global__ __launch_bounds__(1024) void k_gat2(
    const int* __restrict__ sse, const int* __restrict__ bsc,
    const int* __restrict__ sue,
    const float* __restrict__ t1B, const float* __restrict__ t2B,
    const unsigned short* __restrict__ hp2bf,
    const unsigned short* __restrict__ WintT,
    float* __restrict__ hp3)
{
    __shared__ __align__(16) unsigned s_rows[16][72];
    int wave = threadIdx.x >> 6;
    int lane = threadIdx.x & 63;
    int row  = blockIdx.x * 16 + wave;
    int n    = row - 1;

    float gn = 0.f, gm = 0.f;
    if (n >= 0 && n < N_NODES) {
        int kidx = 0, ksu = 0;
        float lg = NEG_INF_F;
        if (lane < K_NB) {
            kidx = sse[n * K_NB + lane];
            int ke = bsc[n * K_NB + lane];
            ksu = sue[ke];
            float p = t1B[kidx] + t2B[ksu];
            p = (p > 0.f) ? p : 0.2f * p;
            lg = (kidx == 0) ? NEG_INF_F : p;
        }
        unsigned wn_u[K_NB], wm_u[K_NB];
        int off = lane * 2;
#pragma unroll
        for (int k = 0; k < K_NB; ++k) {
            const unsigned short* pk = hp2bf + (size_t)readlane_i(kidx, k) * H;
            GLOAD_U16(wn_u[k], off, pk);
        }
#pragma unroll
        for (int k = 0; k < K_NB; ++k) {
            const unsigned short* ps = hp2bf + (size_t)readlane_i(ksu, k) * H;
            GLOAD_U16(wm_u[k], off, ps);
        }
        float m = lg;
#pragma unroll
        for (int o = 8; o > 0; o >>= 1) m = fmaxf(m, __shfl_xor(m, o, 64));
        float ex = __expf(lg - m);
        float s = ex;
#pragma unroll
        for (int o = 8; o > 0; o >>= 1) s += __shfl_xor(s, o, 64);
        float alpha = ex / s;

        DRAIN16(wn_u);
        HOLD16(wm_u);
#pragma unroll
        for (int k = 0; k < K_NB; ++k) {
            float ak = readlane_f(alpha, k);
            gn += ak * bf2f(wn_u[k]);
            gm += ak * bf2f(wm_u[k]);
        }
    }
    s_rows[wave][lane] = (unsigned)f2bf(gn) | ((unsigned)f2bf(gm) << 16);
    __syncthreads();

    if (wave < 4) {
        int t = wave;
        int m = lane & 15, q = lane >> 4;
        bf16x8 bfr[4];
        const unsigned short* bp = WintT + (size_t)(t * 16 + m) * 128 + q * 8;
#pragma unroll
        for (int kk = 0; kk < 4; ++kk) {
            UB ub; ub.u = *(const uint4*)(bp + kk * 32);
            bfr[kk] = ub.v;
        }
        f32x4 acc = (f32x4){0.f, 0.f, 0.f, 0.f};
#pragma unroll
        for (int kk = 0; kk < 4; ++kk) {
            UB ua; ua.u = *(const uint4*)&s_rows[m][kk * 16 + q * 4];
            acc = __builtin_amdgcn_mfma_f32_16x16x32_bf16(ua.v, bfr[kk], acc, 0, 0, 0);
        }
        int row0 = blockIdx.x * 16;
#pragma unroll
        for (int r = 0; r < 4; ++r) {
            int rr = row0 + q * 4 + r;
            if (rr <= N_NODES) {
                float v = acc[r];
                hp3[(size_t)rr * H + t * 16 + m] = (v > 0.f) ? v : expm1f(v);
            }
        }
    }
}

// ---------------------------------------------------------------------------
// out[b] = sum_m hp3[l_scope[b,m]] — 48 raw asm gathers all in flight.
// ---------------------------------------------------------------------------
__global__ __launch_bounds__(256) void k_out(
    const int* __restrict__ l_scope, const float* __restrict__ hp,
    float* __restrict__ out)
{
    int wave = threadIdx.x >> 6;
    int lane = threadIdx.x & 63;
    int b = blockIdx.x * 4 + wave;
    if (b >= B_MOL) return;
    int idx48 = (lane < MAXM_M) ? l_scope[b * MAXM_M + lane] : 0;
    float v[MAXM_M];
    int off = lane * 4;
#pragma unroll
    for (int m = 0; m < MAXM_M; ++m) {
        const float* pm = hp + (size_t)readlane_i(idx48, m) * H;
        GLOAD_F32(v[m], off, pm);
    }
    asm volatile("s_waitcnt vmcnt(0)"
        : "+v"(v[0]), "+v"(v[1]), "+v"(v[2]), "+v"(v[3]),
          "+v"(v[4]), "+v"(v[5]), "+v"(v[6]), "+v"(v[7]),
          "+v"(v[8]), "+v"(v[9]), "+v"(v[10]), "+v"(v[11]),
          "+v"(v[12]), "+v"(v[13]), "+v"(v[14]), "+v"(v[15]));
    asm volatile(""
        : "+v"(v[16]), "+v"(v[17]), "+v"(v[18]), "+v"(v[19]),
          "+v"(v[20]), "+v"(v[21]), "+v"(v[22]), "+v"(v[23]),
          "+v"(v[24]), "+v"(v[25]), "+v"(v[26]), "+v"(v[27]),
          "+v"(v[28]), "+v"(v[29]), "+v"(v[30]), "+v"(v[31]));
    asm volatile(""
        : "+v"(v[32]), "+v"(v[33]), "+v"(v[34]), "+v"(v[35]),
          "+v"(v[36]), "+v"(v[37]), "+v"(v[38]), "+v"(v[39]),
          "+v"(v[40]), "+v"(v[41]), "+v"(v[42]), "+v"(v[43]),
          "+v"(v[44]), "+v"(v[45]), "+v"(v[46]), "+v"(v[47]));
    float acc = 0.f;
#pragma unroll
    for (int m = 0; m < MAXM_M; ++m) acc += v[m];
    out[b * H + lane] = acc;
}

extern "C" void kernel_launch(void* const* d_in, const int* in_sizes, int n_in,
                              void* d_out, int out_size, void* d_ws, size_t ws_size,
                              hipStream_t stream)
{
    const float* tf     = (const float*)d_in[0];
    const float* fdg    = (const float*)d_in[1];
    const float* rij    = (const float*)d_in[2];
    const int*   sse    = (const int*)d_in[3];
    const int*   bsc    = (const int*)d_in[4];
    const int*   lsc    = (const int*)d_in[5];
    const int*   su     = (const int*)d_in[6];
    const int*   sul    = (const int*)d_in[7];
    const float* W_emb  = (const float*)d_in[8];
    const float* b_emb  = (const float*)d_in[9];
    const float* W_dist = (const float*)d_in[10];
    const float* b_dist = (const float*)d_in[11];
    const float* W_gat  = (const float*)d_in[12];
    const float* Wm_gat = (const float*)d_in[13];
    const float* a_gat  = (const float*)d_in[14];
    float* out = (float*)d_out;

    char* base = (char*)d_ws;
    size_t off = 0;
    auto alloc = [&](size_t bytes) {
        char* p = base + off;
        off = (off + bytes + 255) & ~(size_t)255;
        return p;
    };
    float* wa   = (float*)alloc(16 * 4);
    float* ca   = (float*)alloc(16 * 4);
    float* wv9  = (float*)alloc(16 * 4);
    float* cv   = (float*)alloc(16 * 4);
    unsigned short* WintT = (unsigned short*)alloc(64 * 128 * 2);
    unsigned short* WcatT = (unsigned short*)alloc(64 * 32 * 2);
    unsigned short* vabT  = (unsigned short*)alloc(16 * 64 * 2);
    float* t1A  = (float*)alloc((size_t)(N_NODES + 1) * 4);
    float* t1B  = (float*)alloc((size_t)(N_NODES + 1) * 4);
    float* t2B  = (float*)alloc((size_t)(N_NODES + 1) * 4);
    int*   sue  = (int*)alloc((size_t)E_EDGES * 4);
    unsigned short* tfp   = (unsigned short*)alloc((size_t)(N_NODES + 1) * 16 * 2);
    unsigned short* hp2bf = (unsigned short*)alloc((size_t)(N_NODES + 1) * H * 2);
    // emsg (25.6MB) and hp3 (12.8MB) alias: emsg dead before k_gat2 writes hp3
    char* big = alloc((size_t)E_EDGES * 32);
    unsigned short* emsg = (unsigned short*)big;
    float* hp3 = (float*)big;

    k_fold<<<dim3(1), dim3(256), 0, stream>>>(
        W_emb, b_emb, W_dist, b_dist, W_gat, Wm_gat, a_gat,
        wa, ca, wv9, cv, WintT, WcatT, vabT);

    k_pre<<<dim3(PRE_NODE_BLOCKS + EDGE_BLOCKS), dim3(256), 0, stream>>>(
        tf, fdg, rij, su, sul, wa, ca, wv9, cv, t1A, tfp, emsg, sue);

    k_gat1<<<dim3((N_NODES + 16) / 16), dim3(1024), 0, stream>>>(
        sse, bsc, t1A, tfp, emsg, WcatT, vabT, hp2bf, t1B, t2B);

    k_gat2<<<dim3((N_NODES + 16) / 16), dim3(1024), 0, stream>>>(
        sse, bsc, sue, t1B, t2B, hp2bf, WintT, hp3);

    k_out<<<dim3(B_MOL / 4), dim3(256), 0, stream>>>(lsc, hp3, out);
}